// Round 4
// baseline (651.887 us; speedup 1.0000x reference)
//
#include <hip/hip_runtime.h>
#include <math.h>

#define kB 128
#define kS 50
#define kD 64
#define kL 2
#define kItems 50000
#define kEps 1e-5f
#define PAD 68   // floats; row byte stride 272 -> float4-aligned rows, row-wise access conflict-free

typedef __bf16 bf16x8 __attribute__((ext_vector_type(8)));
typedef float  f32x4v __attribute__((ext_vector_type(4)));

__device__ __forceinline__ float wsum(float v) {
#pragma unroll
    for (int off = 32; off; off >>= 1) v += __shfl_xor(v, off, 64);
    return v;
}
__device__ __forceinline__ float wmax(float v) {
#pragma unroll
    for (int off = 32; off; off >>= 1) v = fmaxf(v, __shfl_xor(v, off, 64));
    return v;
}
__device__ __forceinline__ unsigned short f2bf(float x) {  // RNE
    unsigned u = __builtin_bit_cast(unsigned, x);
    u += 0x7FFFu + ((u >> 16) & 1u);
    return (unsigned short)(u >> 16);
}
__device__ __forceinline__ float dot4(const float4 a, const float4 b) {
    return fmaf(a.x, b.x, fmaf(a.y, b.y, fmaf(a.z, b.z, a.w * b.w)));
}

// One block (512 threads) per batch element. Whole [S,D] activation set in LDS.
__global__ __launch_bounds__(512) void transformer_kernel(
    const int* __restrict__ item_ids, const float* __restrict__ emb,
    const float* __restrict__ pos_emb,
    const float* __restrict__ Wq, const float* __restrict__ Wk,
    const float* __restrict__ Wv,
    const float* __restrict__ W1, const float* __restrict__ b1,
    const float* __restrict__ W2, const float* __restrict__ b2,
    const float* __restrict__ ln_g, const float* __restrict__ ln_b,
    unsigned short* __restrict__ Xb)   // [B*S, D] bf16 output
{
    const int b    = blockIdx.x;
    const int tid  = threadIdx.x;
    const int lane = tid & 63;
    const int wave = tid >> 6;

    __shared__ float xs[kS][PAD];
    __shared__ float qs[kS][PAD];   // Q, later reused for FFN output
    __shared__ float ks[kS][PAD];
    __shared__ float vs[kS][PAD];
    __shared__ float as[kS][PAD];   // attention out, later reused for hidden h
    __shared__ float ps[8][64];     // per-wave softmax row

    for (int i = tid; i < kS * kD; i += 512) {
        int s = i >> 6, d = i & 63;
        int item = item_ids[b * kS + s];
        xs[s][d] = emb[(size_t)item * kD + d] + pos_emb[s * kD + d];
    }
    __syncthreads();

    for (int l = 0; l < kL; ++l) {
        const float* wq = Wq + l * kD * kD;
        const float* wk = Wk + l * kD * kD;
        const float* wv = Wv + l * kD * kD;
        const float* g  = ln_g + l * kD;
        const float* be = ln_b + l * kD;

        // Q,K,V = x @ W.T
        for (int i = tid; i < 3 * kS * kD; i += 512) {
            int m = i / (kS * kD);
            int r = i % (kS * kD);
            int s = r >> 6, e = r & 63;
            const float4* w  = (const float4*)((m == 0 ? wq : m == 1 ? wk : wv) + e * kD);
            const float4* xv = (const float4*)&xs[s][0];
            float acc = 0.f;
#pragma unroll
            for (int d4 = 0; d4 < 16; ++d4) acc += dot4(xv[d4], w[d4]);
            float* dst = (m == 0 ? &qs[0][0] : m == 1 ? &ks[0][0] : &vs[0][0]);
            dst[s * PAD + e] = acc;
        }
        __syncthreads();

        // causal attention: one wave per q-row
        for (int q = wave; q < kS; q += 8) {
            int k = lane;
            float sc = -INFINITY;
            if (k <= q) {
                const float4* qv = (const float4*)&qs[q][0];
                const float4* kv = (const float4*)&ks[k][0];
                float acc = 0.f;
#pragma unroll
                for (int d4 = 0; d4 < 16; ++d4) acc += dot4(qv[d4], kv[d4]);
                sc = acc * 0.125f;
            }
            float mx = wmax(sc);
            float ev = (k <= q) ? __expf(sc - mx) : 0.f;
            float sm = wsum(ev);
            ps[wave][lane] = ev / sm;
            float acc = 0.f;
            for (int kk = 0; kk <= q; ++kk)
                acc = fmaf(ps[wave][kk], vs[kk][lane], acc);
            as[q][lane] = acc;
        }
        __syncthreads();

        // x = LN(x + attn)
        for (int s = wave; s < kS; s += 8) {
            float v  = xs[s][lane] + as[s][lane];
            float mu = wsum(v) * (1.f / 64.f);
            float dv = v - mu;
            float var = wsum(dv * dv) * (1.f / 64.f);
            xs[s][lane] = fmaf(g[lane] * dv, rsqrtf(var + kEps), be[lane]);
        }
        __syncthreads();

        // h = relu(x @ W1.T + b1)
        for (int i = tid; i < kS * kD; i += 512) {
            int s = i >> 6, e = i & 63;
            const float4* w  = (const float4*)(W1 + l * kD * kD + e * kD);
            const float4* xv = (const float4*)&xs[s][0];
            float acc = b1[l * kD + e];
#pragma unroll
            for (int d4 = 0; d4 < 16; ++d4) acc += dot4(xv[d4], w[d4]);
            as[s][e] = fmaxf(acc, 0.f);
        }
        __syncthreads();

        // ff = h @ W2.T + b2  -> qs
        for (int i = tid; i < kS * kD; i += 512) {
            int s = i >> 6, e = i & 63;
            const float4* w  = (const float4*)(W2 + l * kD * kD + e * kD);
            const float4* hv = (const float4*)&as[s][0];
            float acc = b2[l * kD + e];
#pragma unroll
            for (int d4 = 0; d4 < 16; ++d4) acc += dot4(hv[d4], w[d4]);
            qs[s][e] = acc;
        }
        __syncthreads();

        // x = LN(x + ff)
        for (int s = wave; s < kS; s += 8) {
            float v  = xs[s][lane] + qs[s][lane];
            float mu = wsum(v) * (1.f / 64.f);
            float dv = v - mu;
            float var = wsum(dv * dv) * (1.f / 64.f);
            xs[s][lane] = fmaf(g[lane] * dv, rsqrtf(var + kEps), be[lane]);
        }
        __syncthreads();
    }

    for (int i = tid; i < kS * kD; i += 512) {
        int s = i >> 6, d = i & 63;
        Xb[(size_t)(b * kS + s) * kD + d] = f2bf(xs[s][d]);
    }
}

// logits[m][n] = sum_d X[m][d] * E[n][d]
// One block per 64-wide n-strip. E staged once (bf16, swizzled LDS), E-fragments
// hoisted to registers; m-loop reads X fragments DIRECTLY from global (L2-resident),
// no barriers, nontemporal float4 C-stores so the 1.25 GB write stream doesn't
// evict Xb from L2 (round-1 FETCH_SIZE=631MB == Xb re-read stream going to HBM).
__global__ __launch_bounds__(256) void logits_kernel(
    const unsigned short* __restrict__ Xb, const float* __restrict__ E,
    float* __restrict__ out)
{
    const int tid  = threadIdx.x;
    const int lane = tid & 63;
    const int wave = tid >> 6;
    const int n0   = blockIdx.x * 64;

    __shared__ __align__(16) unsigned short Es[64 * 64];  // swizzled [n][k] bf16

    // stage E strip, converting f32 -> bf16
    for (int i = tid; i < 64 * 16; i += 256) {
        int r  = i >> 4;           // local n
        int c4 = (i & 15) * 4;     // k
        int n  = n0 + r;
        float4 v = (n < kItems) ? *(const float4*)&E[(size_t)n * kD + c4]
                                : make_float4(0.f, 0.f, 0.f, 0.f);
        ushort4 u;
        u.x = f2bf(v.x); u.y = f2bf(v.y); u.z = f2bf(v.z); u.w = f2bf(v.w);
        int byte = (r * 128 + c4 * 2) ^ ((r & 7) << 4);
        *(ushort4*)((char*)Es + byte) = u;
    }
    __syncthreads();

    const int frow = lane & 15;    // fragment row index
    const int kq   = lane >> 4;    // k-quarter 0..3

    // hoist E-fragments (A operand): 4 n-chunks x 2 k-steps
    bf16x8 efrag[4][2];
#pragma unroll
    for (int nc = 0; nc < 4; ++nc) {
        int brow = nc * 16 + frow;
        int base = brow * 128 + kq * 16;
        int swz  = (brow & 7) << 4;
        efrag[nc][0] = *(const bf16x8*)((const char*)Es + ((base) ^ swz));
        efrag[nc][1] = *(const bf16x8*)((const char*)Es + ((base + 64) ^ swz));
    }

    // X fragment (B operand): row = m0 + wave*16 + frow, k = kq*8
    const unsigned short* xrow = Xb + ((size_t)(wave * 16 + frow)) * kD + kq * 8;

    for (int mt = 0; mt < 100; ++mt) {
        const size_t moff = (size_t)mt * 64 * kD;
        bf16x8 x0 = *(const bf16x8*)(xrow + moff);        // k 0..31 slice
        bf16x8 x1 = *(const bf16x8*)(xrow + moff + 32);   // k 32..63 slice

        f32x4v acc[4];
#pragma unroll
        for (int nc = 0; nc < 4; ++nc) {
            acc[nc] = (f32x4v){0.f, 0.f, 0.f, 0.f};
            acc[nc] = __builtin_amdgcn_mfma_f32_16x16x32_bf16(efrag[nc][0], x0, acc[nc], 0, 0, 0);
            acc[nc] = __builtin_amdgcn_mfma_f32_16x16x32_bf16(efrag[nc][1], x1, acc[nc], 0, 0, 0);
        }

        // D layout: col(lane&15) = m-local, row((lane>>4)*4+reg) = n-local
        const int m = mt * 64 + wave * 16 + frow;
#pragma unroll
        for (int nc = 0; nc < 4; ++nc) {
            int n = n0 + nc * 16 + kq * 4;
            if (n0 + nc * 16 < kItems) {   // kItems % 16 == 0 -> whole chunk valid
                __builtin_nontemporal_store(acc[nc],
                    (f32x4v*)(out + (size_t)m * kItems + n));
            }
        }
    }
}

extern "C" void kernel_launch(void* const* d_in, const int* in_sizes, int n_in,
                              void* d_out, int out_size, void* d_ws, size_t ws_size,
                              hipStream_t stream) {
    const int*   item_ids = (const int*)d_in[0];
    const float* emb      = (const float*)d_in[1];
    const float* pos_emb  = (const float*)d_in[2];
    const float* Wq       = (const float*)d_in[3];
    const float* Wk       = (const float*)d_in[4];
    const float* Wv       = (const float*)d_in[5];
    const float* W1       = (const float*)d_in[6];
    const float* b1       = (const float*)d_in[7];
    const float* W2       = (const float*)d_in[8];
    const float* b2       = (const float*)d_in[9];
    const float* ln_g     = (const float*)d_in[10];
    const float* ln_b     = (const float*)d_in[11];

    unsigned short* Xb = (unsigned short*)d_ws;   // [B*S, D] bf16, 0.8 MB
    float* out = (float*)d_out;

    transformer_kernel<<<kB, 512, 0, stream>>>(item_ids, emb, pos_emb,
                                               Wq, Wk, Wv, W1, b1, W2, b2,
                                               ln_g, ln_b, Xb);
    const int nblocks = (kItems + 63) / 64;   // 782
    logits_kernel<<<nblocks, 256, 0, stream>>>(Xb, emb, out);
}

// Round 5
// 472.774 us; speedup vs baseline: 1.3789x; 1.3789x over previous
//
#include <hip/hip_runtime.h>
#include <math.h>

#define kB 128
#define kS 50
#define kD 64
#define kL 2
#define kItems 50000
#define kEps 1e-5f
#define PAD 68     // floats; row byte stride 272 (16-aligned) -> float4 rows, conflict-spread columns
#define NSTRIP 256
#define MT_PER 50

typedef __bf16 bf16x8 __attribute__((ext_vector_type(8)));
typedef float  f32x4v __attribute__((ext_vector_type(4)));

__device__ __forceinline__ float wsum(float v) {
#pragma unroll
    for (int off = 32; off; off >>= 1) v += __shfl_xor(v, off, 64);
    return v;
}
__device__ __forceinline__ float wmax(float v) {
#pragma unroll
    for (int off = 32; off; off >>= 1) v = fmaxf(v, __shfl_xor(v, off, 64));
    return v;
}
__device__ __forceinline__ unsigned short f2bf(float x) {  // RNE
    unsigned u = __builtin_bit_cast(unsigned, x);
    u += 0x7FFFu + ((u >> 16) & 1u);
    return (unsigned short)(u >> 16);
}
__device__ __forceinline__ float dot4(const float4 a, const float4 b) {
    return fmaf(a.x, b.x, fmaf(a.y, b.y, fmaf(a.z, b.z, a.w * b.w)));
}

// One block (512 threads) per batch element. Activations + current weight matrix in LDS.
__global__ __launch_bounds__(512) void transformer_kernel(
    const int* __restrict__ item_ids, const float* __restrict__ emb,
    const float* __restrict__ pos_emb,
    const float* __restrict__ Wq, const float* __restrict__ Wk,
    const float* __restrict__ Wv,
    const float* __restrict__ W1, const float* __restrict__ b1,
    const float* __restrict__ W2, const float* __restrict__ b2,
    const float* __restrict__ ln_g, const float* __restrict__ ln_b,
    unsigned short* __restrict__ Xb)   // [B*S, D] bf16 output
{
    const int b    = blockIdx.x;
    const int tid  = threadIdx.x;
    const int lane = tid & 63;
    const int wave = tid >> 6;

    __shared__ float xs[kS][PAD];
    __shared__ float qs[kS][PAD];   // Q, later reused for FFN output
    __shared__ float ks[kS][PAD];
    __shared__ float vs[kS][PAD];
    __shared__ float as[kS][PAD];   // attention out, later reused for hidden h
    __shared__ float ps[8][64];     // per-wave softmax row
    __shared__ float Ws[kD][PAD];   // staged weight matrix (one at a time)

    for (int i = tid; i < kS * kD; i += 512) {
        int s = i >> 6, d = i & 63;
        int item = item_ids[b * kS + s];
        xs[s][d] = emb[(size_t)item * kD + d] + pos_emb[s * kD + d];
    }
    __syncthreads();

    for (int l = 0; l < kL; ++l) {
        const float* g  = ln_g + l * kD;
        const float* be = ln_b + l * kD;

        // ---- 3 GEMM sub-phases: Q, K, V (weights staged in LDS) ----
#pragma unroll
        for (int m = 0; m < 3; ++m) {
            const float* W = (m == 0 ? Wq : m == 1 ? Wk : Wv) + l * kD * kD;
            for (int i = tid; i < kD * 16; i += 512) {
                int r = i >> 4, c4 = (i & 15) * 4;
                *(float4*)&Ws[r][c4] = *(const float4*)&W[r * kD + c4];
            }
            __syncthreads();
            float* dst = (m == 0 ? &qs[0][0] : m == 1 ? &ks[0][0] : &vs[0][0]);
            for (int i = tid; i < kS * kD; i += 512) {
                int s = i >> 6, e = i & 63;
                const float4* w  = (const float4*)&Ws[e][0];
                const float4* xv = (const float4*)&xs[s][0];
                float acc = 0.f;
#pragma unroll
                for (int d4 = 0; d4 < 16; ++d4) acc += dot4(xv[d4], w[d4]);
                dst[s * PAD + e] = acc;
            }
            __syncthreads();
        }

        // causal attention: one wave per q-row
        for (int q = wave; q < kS; q += 8) {
            int k = lane;
            float sc = -INFINITY;
            if (k <= q) {
                const float4* qv = (const float4*)&qs[q][0];
                const float4* kv = (const float4*)&ks[k][0];
                float acc = 0.f;
#pragma unroll
                for (int d4 = 0; d4 < 16; ++d4) acc += dot4(qv[d4], kv[d4]);
                sc = acc * 0.125f;
            }
            float mx = wmax(sc);
            float ev = (k <= q) ? __expf(sc - mx) : 0.f;   // 0 beyond q -> ps zero-padded
            float sm = wsum(ev);
            ps[wave][lane] = ev / sm;
            float acc = 0.f;
#pragma unroll
            for (int kk = 0; kk < kS; ++kk)                 // fixed trip: unrollable, pipelined
                acc = fmaf(ps[wave][kk], vs[kk][lane], acc);
            as[q][lane] = acc;
        }
        __syncthreads();

        // x = LN(x + attn)
        for (int s = wave; s < kS; s += 8) {
            float v  = xs[s][lane] + as[s][lane];
            float mu = wsum(v) * (1.f / 64.f);
            float dv = v - mu;
            float var = wsum(dv * dv) * (1.f / 64.f);
            xs[s][lane] = fmaf(g[lane] * dv, rsqrtf(var + kEps), be[lane]);
        }
        __syncthreads();

        // h = relu(x @ W1.T + b1)   (W1 staged)
        for (int i = tid; i < kD * 16; i += 512) {
            int r = i >> 4, c4 = (i & 15) * 4;
            *(float4*)&Ws[r][c4] = *(const float4*)&W1[l * kD * kD + r * kD + c4];
        }
        __syncthreads();
        for (int i = tid; i < kS * kD; i += 512) {
            int s = i >> 6, e = i & 63;
            const float4* w  = (const float4*)&Ws[e][0];
            const float4* xv = (const float4*)&xs[s][0];
            float acc = b1[l * kD + e];
#pragma unroll
            for (int d4 = 0; d4 < 16; ++d4) acc += dot4(xv[d4], w[d4]);
            as[s][e] = fmaxf(acc, 0.f);
        }
        __syncthreads();

        // ff = h @ W2.T + b2 -> qs   (W2 staged)
        for (int i = tid; i < kD * 16; i += 512) {
            int r = i >> 4, c4 = (i & 15) * 4;
            *(float4*)&Ws[r][c4] = *(const float4*)&W2[l * kD * kD + r * kD + c4];
        }
        __syncthreads();
        for (int i = tid; i < kS * kD; i += 512) {
            int s = i >> 6, e = i & 63;
            const float4* w  = (const float4*)&Ws[e][0];
            const float4* hv = (const float4*)&as[s][0];
            float acc = b2[l * kD + e];
#pragma unroll
            for (int d4 = 0; d4 < 16; ++d4) acc += dot4(hv[d4], w[d4]);
            qs[s][e] = acc;
        }
        __syncthreads();

        // x = LN(x + ff)
        for (int s = wave; s < kS; s += 8) {
            float v  = xs[s][lane] + qs[s][lane];
            float mu = wsum(v) * (1.f / 64.f);
            float dv = v - mu;
            float var = wsum(dv * dv) * (1.f / 64.f);
            xs[s][lane] = fmaf(g[lane] * dv, rsqrtf(var + kEps), be[lane]);
        }
        __syncthreads();
    }

    for (int i = tid; i < kS * kD; i += 512) {
        int s = i >> 6, d = i & 63;
        Xb[(size_t)(b * kS + s) * kD + d] = f2bf(xs[s][d]);
    }
}

// logits[m][n] = sum_d X[m][d] * E[n][d]
// 392 blocks = 196 n-strips (256 wide) x 2 m-halves; 1024 threads = 16 waves (mw,nw).
// E strip staged once (bf16, swizzled); X m-tile (8KB) double-buffered in LDS per iter
// (issue-early global load, write-late). Per block-iter each output row gets 1KB
// CONTIGUOUS writes -> DRAM page locality (fix for the ~2.5TB/s write plateau).
__global__ __launch_bounds__(1024) void logits_kernel(
    const unsigned short* __restrict__ Xb, const float* __restrict__ E,
    float* __restrict__ out)
{
    const int tid  = threadIdx.x;
    const int lane = tid & 63;
    const int wave = tid >> 6;          // 0..15
    const int n0   = blockIdx.x * NSTRIP;
    const int mt0  = blockIdx.y * MT_PER;

    __shared__ __align__(16) unsigned short Es[NSTRIP * kD];  // 32KB swizzled [n][k] bf16
    __shared__ __align__(16) unsigned short Xs[2][64 * kD];   // 2 x 8KB swizzled [m][k] bf16

    // stage E strip, f32 -> bf16
    for (int i = tid; i < NSTRIP * 16; i += 1024) {
        int r  = i >> 4;
        int c4 = (i & 15) * 4;
        int n  = n0 + r;
        float4 v = (n < kItems) ? *(const float4*)&E[(size_t)n * kD + c4]
                                : make_float4(0.f, 0.f, 0.f, 0.f);
        ushort4 u;
        u.x = f2bf(v.x); u.y = f2bf(v.y); u.z = f2bf(v.z); u.w = f2bf(v.w);
        int byte = (r * 128 + c4 * 2) ^ ((r & 7) << 4);
        *(ushort4*)((char*)Es + byte) = u;
    }

    const int frow = lane & 15;
    const int kq   = lane >> 4;
    const int mw   = wave & 3;          // m-subtile 0..3
    const int nw   = wave >> 2;         // n-group of 64: 0..3

    // X loader params (first 512 threads): tile byte p, swizzled LDS dest
    const int  p      = (tid & 511) * 16;
    const int  xrow_l = p >> 7;
    const int  pswz   = p ^ ((xrow_l & 7) << 4);
    const bool loader = tid < 512;

    // prologue: stage first X tile (tile rows are contiguous: full row = 128B)
    if (loader) {
        float4 v = *(const float4*)((const char*)Xb + (size_t)mt0 * 8192 + p);
        *(float4*)((char*)&Xs[0][0] + pswz) = v;
    }
    __syncthreads();   // Es + Xs[0] ready

    // hoist E-fragments for this wave's 64-n group
    bf16x8 efrag[4][2];
#pragma unroll
    for (int nc = 0; nc < 4; ++nc) {
        int brow = nw * 64 + nc * 16 + frow;
        int base = brow * 128 + kq * 16;
        int swz  = (brow & 7) << 4;
        efrag[nc][0] = *(const bf16x8*)((const char*)Es + ((base) ^ swz));
        efrag[nc][1] = *(const bf16x8*)((const char*)Es + ((base + 64) ^ swz));
    }

    const int xr    = mw * 16 + frow;
    const int xbase = xr * 128 + kq * 16;
    const int xswz  = (xr & 7) << 4;

    int cur = 0;
    for (int t = 0; t < MT_PER; ++t) {
        const int mt = mt0 + t;

        // issue next tile's global load early (T14: hide HBM latency under compute)
        float4 nxt;
        if (t + 1 < MT_PER && loader)
            nxt = *(const float4*)((const char*)Xb + (size_t)(mt + 1) * 8192 + p);

        bf16x8 x0 = *(const bf16x8*)((const char*)&Xs[cur][0] + ((xbase) ^ xswz));
        bf16x8 x1 = *(const bf16x8*)((const char*)&Xs[cur][0] + ((xbase + 64) ^ xswz));

        f32x4v acc[4];
#pragma unroll
        for (int nc = 0; nc < 4; ++nc) {
            acc[nc] = (f32x4v){0.f, 0.f, 0.f, 0.f};
            acc[nc] = __builtin_amdgcn_mfma_f32_16x16x32_bf16(efrag[nc][0], x0, acc[nc], 0, 0, 0);
            acc[nc] = __builtin_amdgcn_mfma_f32_16x16x32_bf16(efrag[nc][1], x1, acc[nc], 0, 0, 0);
        }

        // D layout: col(lane&15)=m-local, row((lane>>4)*4+reg)=n-local
        const int m = mt * 64 + mw * 16 + frow;
#pragma unroll
        for (int nc = 0; nc < 4; ++nc) {
            int nbase = n0 + nw * 64 + nc * 16;
            if (nbase < kItems) {   // chunk of 16 fully valid (kItems % 16 == 0)
                __builtin_nontemporal_store(acc[nc],
                    (f32x4v*)(out + (size_t)m * kItems + nbase + kq * 4));
            }
        }

        // write-late: next tile into the other buffer
        if (t + 1 < MT_PER && loader)
            *(float4*)((char*)&Xs[cur ^ 1][0] + pswz) = nxt;
        __syncthreads();
        cur ^= 1;
    }
}

extern "C" void kernel_launch(void* const* d_in, const int* in_sizes, int n_in,
                              void* d_out, int out_size, void* d_ws, size_t ws_size,
                              hipStream_t stream) {
    const int*   item_ids = (const int*)d_in[0];
    const float* emb      = (const float*)d_in[1];
    const float* pos_emb  = (const float*)d_in[2];
    const float* Wq       = (const float*)d_in[3];
    const float* Wk       = (const float*)d_in[4];
    const float* Wv       = (const float*)d_in[5];
    const float* W1       = (const float*)d_in[6];
    const float* b1       = (const float*)d_in[7];
    const float* W2       = (const float*)d_in[8];
    const float* b2       = (const float*)d_in[9];
    const float* ln_g     = (const float*)d_in[10];
    const float* ln_b     = (const float*)d_in[11];

    unsigned short* Xb = (unsigned short*)d_ws;   // [B*S, D] bf16, 0.8 MB
    float* out = (float*)d_out;

    transformer_kernel<<<kB, 512, 0, stream>>>(item_ids, emb, pos_emb,
                                               Wq, Wk, Wv, W1, b1, W2, b2,
                                               ln_g, ln_b, Xb);
    dim3 grid((kItems + NSTRIP - 1) / NSTRIP, 100 / MT_PER);   // 196 x 2
    logits_kernel<<<grid, 1024, 0, stream>>>(Xb, emb, out);
}

// Round 6
// 318.777 us; speedup vs baseline: 2.0450x; 1.4831x over previous
//
#include <hip/hip_runtime.h>
#include <math.h>

#define kB 128
#define kS 50
#define kD 64
#define kL 2
#define kItems 50000
#define kEps 1e-5f
#define PAD 68     // transformer LDS row stride (floats)
#define NSTRIP 256
#define MROWS 32   // m-rows per logits tile-iter
#define NITER 100  // 3200 rows per m-half / 32

typedef __bf16 bf16x8 __attribute__((ext_vector_type(8)));
typedef float  f32x4v __attribute__((ext_vector_type(4)));

__device__ __forceinline__ float wsum(float v) {
#pragma unroll
    for (int off = 32; off; off >>= 1) v += __shfl_xor(v, off, 64);
    return v;
}
__device__ __forceinline__ float wmax(float v) {
#pragma unroll
    for (int off = 32; off; off >>= 1) v = fmaxf(v, __shfl_xor(v, off, 64));
    return v;
}
__device__ __forceinline__ unsigned short f2bf(float x) {  // RNE
    unsigned u = __builtin_bit_cast(unsigned, x);
    u += 0x7FFFu + ((u >> 16) & 1u);
    return (unsigned short)(u >> 16);
}
__device__ __forceinline__ float dot4(const float4 a, const float4 b) {
    return fmaf(a.x, b.x, fmaf(a.y, b.y, fmaf(a.z, b.z, a.w * b.w)));
}

// One block (512 threads) per batch element. Activations + current weight matrix in LDS.
__global__ __launch_bounds__(512) void transformer_kernel(
    const int* __restrict__ item_ids, const float* __restrict__ emb,
    const float* __restrict__ pos_emb,
    const float* __restrict__ Wq, const float* __restrict__ Wk,
    const float* __restrict__ Wv,
    const float* __restrict__ W1, const float* __restrict__ b1,
    const float* __restrict__ W2, const float* __restrict__ b2,
    const float* __restrict__ ln_g, const float* __restrict__ ln_b,
    unsigned short* __restrict__ Xb)   // [B*S, D] bf16 output
{
    const int b    = blockIdx.x;
    const int tid  = threadIdx.x;
    const int lane = tid & 63;
    const int wave = tid >> 6;

    __shared__ float xs[kS][PAD];
    __shared__ float qs[kS][PAD];
    __shared__ float ks[kS][PAD];
    __shared__ float vs[kS][PAD];
    __shared__ float as[kS][PAD];
    __shared__ float ps[8][64];
    __shared__ float Ws[kD][PAD];   // staged weight matrix (one at a time)

    for (int i = tid; i < kS * kD; i += 512) {
        int s = i >> 6, d = i & 63;
        int item = item_ids[b * kS + s];
        xs[s][d] = emb[(size_t)item * kD + d] + pos_emb[s * kD + d];
    }
    __syncthreads();

    for (int l = 0; l < kL; ++l) {
        const float* g  = ln_g + l * kD;
        const float* be = ln_b + l * kD;

        // ---- Q, K, V GEMMs (weights staged in LDS) ----
#pragma unroll
        for (int m = 0; m < 3; ++m) {
            const float* W = (m == 0 ? Wq : m == 1 ? Wk : Wv) + l * kD * kD;
            for (int i = tid; i < kD * 16; i += 512) {
                int r = i >> 4, c4 = (i & 15) * 4;
                *(float4*)&Ws[r][c4] = *(const float4*)&W[r * kD + c4];
            }
            __syncthreads();
            float* dst = (m == 0 ? &qs[0][0] : m == 1 ? &ks[0][0] : &vs[0][0]);
            for (int i = tid; i < kS * kD; i += 512) {
                int s = i >> 6, e = i & 63;
                const float4* w  = (const float4*)&Ws[e][0];
                const float4* xv = (const float4*)&xs[s][0];
                float acc = 0.f;
#pragma unroll
                for (int d4 = 0; d4 < 16; ++d4) acc += dot4(xv[d4], w[d4]);
                dst[s * PAD + e] = acc;
            }
            __syncthreads();
        }

        // causal attention: one wave per q-row
        for (int q = wave; q < kS; q += 8) {
            int k = lane;
            float sc = -INFINITY;
            if (k <= q) {
                const float4* qv = (const float4*)&qs[q][0];
                const float4* kv = (const float4*)&ks[k][0];
                float acc = 0.f;
#pragma unroll
                for (int d4 = 0; d4 < 16; ++d4) acc += dot4(qv[d4], kv[d4]);
                sc = acc * 0.125f;
            }
            float mx = wmax(sc);
            float ev = (k <= q) ? __expf(sc - mx) : 0.f;
            float sm = wsum(ev);
            ps[wave][lane] = ev / sm;
            float acc = 0.f;
#pragma unroll
            for (int kk = 0; kk < kS; ++kk)
                acc = fmaf(ps[wave][kk], vs[kk][lane], acc);
            as[q][lane] = acc;
        }
        __syncthreads();

        // x = LN(x + attn)
        for (int s = wave; s < kS; s += 8) {
            float v  = xs[s][lane] + as[s][lane];
            float mu = wsum(v) * (1.f / 64.f);
            float dv = v - mu;
            float var = wsum(dv * dv) * (1.f / 64.f);
            xs[s][lane] = fmaf(g[lane] * dv, rsqrtf(var + kEps), be[lane]);
        }
        __syncthreads();

        // h = relu(x @ W1.T + b1)
        for (int i = tid; i < kD * 16; i += 512) {
            int r = i >> 4, c4 = (i & 15) * 4;
            *(float4*)&Ws[r][c4] = *(const float4*)&W1[l * kD * kD + r * kD + c4];
        }
        __syncthreads();
        for (int i = tid; i < kS * kD; i += 512) {
            int s = i >> 6, e = i & 63;
            const float4* w  = (const float4*)&Ws[e][0];
            const float4* xv = (const float4*)&xs[s][0];
            float acc = b1[l * kD + e];
#pragma unroll
            for (int d4 = 0; d4 < 16; ++d4) acc += dot4(xv[d4], w[d4]);
            as[s][e] = fmaxf(acc, 0.f);
        }
        __syncthreads();

        // ff = h @ W2.T + b2 -> qs
        for (int i = tid; i < kD * 16; i += 512) {
            int r = i >> 4, c4 = (i & 15) * 4;
            *(float4*)&Ws[r][c4] = *(const float4*)&W2[l * kD * kD + r * kD + c4];
        }
        __syncthreads();
        for (int i = tid; i < kS * kD; i += 512) {
            int s = i >> 6, e = i & 63;
            const float4* w  = (const float4*)&Ws[e][0];
            const float4* hv = (const float4*)&as[s][0];
            float acc = b2[l * kD + e];
#pragma unroll
            for (int d4 = 0; d4 < 16; ++d4) acc += dot4(hv[d4], w[d4]);
            qs[s][e] = acc;
        }
        __syncthreads();

        // x = LN(x + ff)
        for (int s = wave; s < kS; s += 8) {
            float v  = xs[s][lane] + qs[s][lane];
            float mu = wsum(v) * (1.f / 64.f);
            float dv = v - mu;
            float var = wsum(dv * dv) * (1.f / 64.f);
            xs[s][lane] = fmaf(g[lane] * dv, rsqrtf(var + kEps), be[lane]);
        }
        __syncthreads();
    }

    for (int i = tid; i < kS * kD; i += 512) {
        int s = i >> 6, d = i & 63;
        Xb[(size_t)(b * kS + s) * kD + d] = f2bf(xs[s][d]);
    }
}

// logits[m][n] = sum_d X[m][d] * E[n][d]
// Block: 512 thr = 8 waves (mw 0..1, nw 0..3); per iter a 32m x 256n tile.
// After MFMA, acc goes through an LDS corner-turn (Cs) so each global store
// is one FULL 1KB-contiguous output-row segment per wave instruction
// (= fillBuffer's pattern; fixes 16-rows-x-64B page-scattered stores).
__global__ __launch_bounds__(512) void logits_kernel(
    const unsigned short* __restrict__ Xb, const float* __restrict__ E,
    float* __restrict__ out)
{
    const int tid  = threadIdx.x;
    const int lane = tid & 63;
    const int wave = tid >> 6;          // 0..7
    const int n0   = blockIdx.x * NSTRIP;
    const int mrow0 = blockIdx.y * (NITER * MROWS);   // m-half base row

    __shared__ __align__(16) unsigned short Es[NSTRIP * kD];   // 32KB swizzled [n][k] bf16
    __shared__ __align__(16) unsigned short Xs[2][MROWS * kD]; // 2 x 4KB swizzled [m][k] bf16
    __shared__ __align__(16) float Cs[MROWS][NSTRIP + 4];      // 33.3KB corner-turn tile

    // stage E strip, f32 -> bf16, swizzled
    for (int i = tid; i < NSTRIP * 16; i += 512) {
        int r  = i >> 4;
        int c4 = (i & 15) * 4;
        int n  = n0 + r;
        float4 v = (n < kItems) ? *(const float4*)&E[(size_t)n * kD + c4]
                                : make_float4(0.f, 0.f, 0.f, 0.f);
        ushort4 u;
        u.x = f2bf(v.x); u.y = f2bf(v.y); u.z = f2bf(v.z); u.w = f2bf(v.w);
        int byte = (r * 128 + c4 * 2) ^ ((r & 7) << 4);
        *(ushort4*)((char*)Es + byte) = u;
    }

    const int frow = lane & 15;
    const int kq   = lane >> 4;
    const int mw   = wave & 1;          // m-subtile 0..1
    const int nw   = wave >> 1;         // n-group of 64: 0..3

    // X loader (first 256 threads): 32 rows x 128B = 4KB tile
    const int  p      = (tid & 255) * 16;
    const int  xrow_l = p >> 7;
    const int  pswz   = p ^ ((xrow_l & 7) << 4);
    const bool loader = tid < 256;

    if (loader) {
        float4 v = *(const float4*)((const char*)Xb + (size_t)mrow0 * 128 + p);
        *(float4*)((char*)&Xs[0][0] + pswz) = v;
    }
    __syncthreads();   // Es + Xs[0] ready

    // hoist E-fragments for this wave's 64-n group
    bf16x8 efrag[4][2];
#pragma unroll
    for (int nc = 0; nc < 4; ++nc) {
        int brow = nw * 64 + nc * 16 + frow;
        int base = brow * 128 + kq * 16;
        int swz  = (brow & 7) << 4;
        efrag[nc][0] = *(const bf16x8*)((const char*)Es + ((base) ^ swz));
        efrag[nc][1] = *(const bf16x8*)((const char*)Es + ((base + 64) ^ swz));
    }

    const int xr    = mw * 16 + frow;
    const int xbase = xr * 128 + kq * 16;
    const int xswz  = (xr & 7) << 4;

    // store-phase constants: wave handles rows wave*4..+3 of the 32-row tile
    const bool ncol_ok = (n0 + lane * 4 + 3) < kItems;   // full float4 in-bounds

    int cur = 0;
    for (int t = 0; t < NITER; ++t) {
        // issue next tile's X load early (hide HBM latency under MFMA+stores)
        float4 nxt;
        if (t + 1 < NITER && loader)
            nxt = *(const float4*)((const char*)Xb +
                    (size_t)(mrow0 + (t + 1) * MROWS) * 128 + p);

        bf16x8 x0 = *(const bf16x8*)((const char*)&Xs[cur][0] + ((xbase) ^ xswz));
        bf16x8 x1 = *(const bf16x8*)((const char*)&Xs[cur][0] + ((xbase + 64) ^ xswz));

        f32x4v acc[4];
#pragma unroll
        for (int nc = 0; nc < 4; ++nc) {
            acc[nc] = (f32x4v){0.f, 0.f, 0.f, 0.f};
            acc[nc] = __builtin_amdgcn_mfma_f32_16x16x32_bf16(efrag[nc][0], x0, acc[nc], 0, 0, 0);
            acc[nc] = __builtin_amdgcn_mfma_f32_16x16x32_bf16(efrag[nc][1], x1, acc[nc], 0, 0, 0);
        }

        // corner-turn: acc -> Cs.  D layout: col(lane&15)=m-local, row((lane>>4)*4+reg)=n-local
#pragma unroll
        for (int nc = 0; nc < 4; ++nc)
            *(f32x4v*)&Cs[mw * 16 + frow][nw * 64 + nc * 16 + kq * 4] = acc[nc];

        if (t + 1 < NITER && loader)
            *(float4*)((char*)&Xs[cur ^ 1][0] + pswz) = nxt;
        __syncthreads();   // Cs complete, Xs[cur^1] staged

        // store: each wave emits 4 rows, each row ONE 1KB-contiguous nt store
        {
            const int mbase = mrow0 + t * MROWS;
#pragma unroll
            for (int rr = 0; rr < 4; ++rr) {
                int r = wave * 4 + rr;
                float4 v = *(const float4*)&Cs[r][lane * 4];
                if (ncol_ok)
                    __builtin_nontemporal_store(*(const f32x4v*)&v,
                        (f32x4v*)(out + (size_t)(mbase + r) * kItems + n0 + lane * 4));
            }
        }
        __syncthreads();   // Cs reads done before next iter overwrites
        cur ^= 1;
    }
}

extern "C" void kernel_launch(void* const* d_in, const int* in_sizes, int n_in,
                              void* d_out, int out_size, void* d_ws, size_t ws_size,
                              hipStream_t stream) {
    const int*   item_ids = (const int*)d_in[0];
    const float* emb      = (const float*)d_in[1];
    const float* pos_emb  = (const float*)d_in[2];
    const float* Wq       = (const float*)d_in[3];
    const float* Wk       = (const float*)d_in[4];
    const float* Wv       = (const float*)d_in[5];
    const float* W1       = (const float*)d_in[6];
    const float* b1       = (const float*)d_in[7];
    const float* W2       = (const float*)d_in[8];
    const float* b2       = (const float*)d_in[9];
    const float* ln_g     = (const float*)d_in[10];
    const float* ln_b     = (const float*)d_in[11];

    unsigned short* Xb = (unsigned short*)d_ws;   // [B*S, D] bf16, 0.8 MB
    float* out = (float*)d_out;

    transformer_kernel<<<kB, 512, 0, stream>>>(item_ids, emb, pos_emb,
                                               Wq, Wk, Wv, W1, b1, W2, b2,
                                               ln_g, ln_b, Xb);
    dim3 grid((kItems + NSTRIP - 1) / NSTRIP, 2);   // 196 x 2
    logits_kernel<<<grid, 512, 0, stream>>>(Xb, emb, out);
}

// Round 7
// 310.550 us; speedup vs baseline: 2.0991x; 1.0265x over previous
//
#include <hip/hip_runtime.h>
#include <math.h>

#define kB 128
#define kS 50
#define kD 64
#define kL 2
#define kItems 50000
#define kEps 1e-5f
#define PAD 68     // transformer LDS row stride (floats)
#define NSTRIP 256
#define MROWS 16   // m-rows per logits tile-iter
#define NITER 200  // 3200 rows per m-half / 16
#define CPAD 260   // Cs row stride (floats)

typedef __bf16 bf16x8 __attribute__((ext_vector_type(8)));
typedef float  f32x4v __attribute__((ext_vector_type(4)));

__device__ __forceinline__ float wsum(float v) {
#pragma unroll
    for (int off = 32; off; off >>= 1) v += __shfl_xor(v, off, 64);
    return v;
}
__device__ __forceinline__ float wmax(float v) {
#pragma unroll
    for (int off = 32; off; off >>= 1) v = fmaxf(v, __shfl_xor(v, off, 64));
    return v;
}
__device__ __forceinline__ unsigned short f2bf(float x) {  // RNE
    unsigned u = __builtin_bit_cast(unsigned, x);
    u += 0x7FFFu + ((u >> 16) & 1u);
    return (unsigned short)(u >> 16);
}
__device__ __forceinline__ float dot4(const float4 a, const float4 b) {
    return fmaf(a.x, b.x, fmaf(a.y, b.y, fmaf(a.z, b.z, a.w * b.w)));
}

// One block (512 threads) per batch element. Activations + staged weights in LDS.
__global__ __launch_bounds__(512) void transformer_kernel(
    const int* __restrict__ item_ids, const float* __restrict__ emb,
    const float* __restrict__ pos_emb,
    const float* __restrict__ Wq, const float* __restrict__ Wk,
    const float* __restrict__ Wv,
    const float* __restrict__ W1, const float* __restrict__ b1,
    const float* __restrict__ W2, const float* __restrict__ b2,
    const float* __restrict__ ln_g, const float* __restrict__ ln_b,
    unsigned short* __restrict__ Xb)   // [B*S, D] bf16 output
{
    const int b    = blockIdx.x;
    const int tid  = threadIdx.x;
    const int lane = tid & 63;
    const int wave = tid >> 6;

    __shared__ float xs[kS][PAD];
    __shared__ float qs[kS][PAD];
    __shared__ float ks[kS][PAD];
    __shared__ float vs[kS][PAD];
    __shared__ float as[kS][PAD];
    __shared__ float ps[8][64];
    __shared__ float Ws[3][kD][PAD];   // staged weights (QKV together / W1+W2)

    for (int i = tid; i < kS * kD; i += 512) {
        int s = i >> 6, d = i & 63;
        int item = item_ids[b * kS + s];
        xs[s][d] = emb[(size_t)item * kD + d] + pos_emb[s * kD + d];
    }
    __syncthreads();

    for (int l = 0; l < kL; ++l) {
        const float* g  = ln_g + l * kD;
        const float* be = ln_b + l * kD;

        // ---- stage Wq,Wk,Wv together, then one compute phase ----
        for (int i = tid; i < 3 * kD * 16; i += 512) {
            int m = i / (kD * 16);
            int r = (i >> 4) % kD;
            int c4 = (i & 15) * 4;
            const float* W = (m == 0 ? Wq : m == 1 ? Wk : Wv) + l * kD * kD;
            *(float4*)&Ws[m][r][c4] = *(const float4*)&W[r * kD + c4];
        }
        __syncthreads();
        for (int i = tid; i < 3 * kS * kD; i += 512) {
            int m = i / (kS * kD);
            int r = i % (kS * kD);
            int s = r >> 6, e = r & 63;
            const float4* w  = (const float4*)&Ws[m][e][0];
            const float4* xv = (const float4*)&xs[s][0];
            float acc = 0.f;
#pragma unroll
            for (int d4 = 0; d4 < 16; ++d4) acc += dot4(xv[d4], w[d4]);
            float* dst = (m == 0 ? &qs[0][0] : m == 1 ? &ks[0][0] : &vs[0][0]);
            dst[s * PAD + e] = acc;
        }
        __syncthreads();

        // causal attention: one wave per q-row
        for (int q = wave; q < kS; q += 8) {
            int k = lane;
            float sc = -INFINITY;
            if (k <= q) {
                const float4* qv = (const float4*)&qs[q][0];
                const float4* kv = (const float4*)&ks[k][0];
                float acc = 0.f;
#pragma unroll
                for (int d4 = 0; d4 < 16; ++d4) acc += dot4(qv[d4], kv[d4]);
                sc = acc * 0.125f;
            }
            float mx = wmax(sc);
            float ev = (k <= q) ? __expf(sc - mx) : 0.f;   // zero-padded beyond q
            float sm = wsum(ev);
            ps[wave][lane] = ev / sm;
            float acc = 0.f;
#pragma unroll
            for (int kk = 0; kk < kS; ++kk)
                acc = fmaf(ps[wave][kk], vs[kk][lane], acc);
            as[q][lane] = acc;
        }
        __syncthreads();

        // x = LN(x + attn); also stage W1,W2 for the FFN in the same phase
        for (int s = wave; s < kS; s += 8) {
            float v  = xs[s][lane] + as[s][lane];
            float mu = wsum(v) * (1.f / 64.f);
            float dv = v - mu;
            float var = wsum(dv * dv) * (1.f / 64.f);
            xs[s][lane] = fmaf(g[lane] * dv, rsqrtf(var + kEps), be[lane]);
        }
        for (int i = tid; i < 2 * kD * 16; i += 512) {
            int m = i / (kD * 16);
            int r = (i >> 4) % kD;
            int c4 = (i & 15) * 4;
            const float* W = (m == 0 ? W1 : W2) + l * kD * kD;
            *(float4*)&Ws[m][r][c4] = *(const float4*)&W[r * kD + c4];
        }
        __syncthreads();

        // h = relu(x @ W1.T + b1)
        for (int i = tid; i < kS * kD; i += 512) {
            int s = i >> 6, e = i & 63;
            const float4* w  = (const float4*)&Ws[0][e][0];
            const float4* xv = (const float4*)&xs[s][0];
            float acc = b1[l * kD + e];
#pragma unroll
            for (int d4 = 0; d4 < 16; ++d4) acc += dot4(xv[d4], w[d4]);
            as[s][e] = fmaxf(acc, 0.f);
        }
        __syncthreads();

        // ff = h @ W2.T + b2 -> qs
        for (int i = tid; i < kS * kD; i += 512) {
            int s = i >> 6, e = i & 63;
            const float4* w  = (const float4*)&Ws[1][e][0];
            const float4* hv = (const float4*)&as[s][0];
            float acc = b2[l * kD + e];
#pragma unroll
            for (int d4 = 0; d4 < 16; ++d4) acc += dot4(hv[d4], w[d4]);
            qs[s][e] = acc;
        }
        __syncthreads();

        // x = LN(x + ff)
        for (int s = wave; s < kS; s += 8) {
            float v  = xs[s][lane] + qs[s][lane];
            float mu = wsum(v) * (1.f / 64.f);
            float dv = v - mu;
            float var = wsum(dv * dv) * (1.f / 64.f);
            xs[s][lane] = fmaf(g[lane] * dv, rsqrtf(var + kEps), be[lane]);
        }
        __syncthreads();
    }

    for (int i = tid; i < kS * kD; i += 512) {
        int s = i >> 6, d = i & 63;
        Xb[(size_t)(b * kS + s) * kD + d] = f2bf(xs[s][d]);
    }
}

// logits[m][n] = sum_d X[m][d] * E[n][d]
// Block: 512 thr = 8 waves, each wave owns a 32-wide n-group of the 256-n strip.
// Per iter: 16m x 256n tile. Double-buffered LDS corner-turn (Cs[2]): iter t
// issues tile t-1's 1KB-contiguous nt row-stores FIRST, then MFMA+corner-turn
// of tile t, then ONE barrier -> stores retire under compute instead of being
// drained immediately by the barrier's vmcnt(0). X fragments read directly
// from global (identical addrs across waves -> L1 broadcast; L2-resident),
// register-prefetched one tile ahead.
__global__ __launch_bounds__(512) void logits_kernel(
    const unsigned short* __restrict__ Xb, const float* __restrict__ E,
    float* __restrict__ out)
{
    const int tid  = threadIdx.x;
    const int lane = tid & 63;
    const int wave = tid >> 6;          // 0..7 = n-group of 32
    const int n0   = blockIdx.x * NSTRIP;
    const int mrow0 = blockIdx.y * (NITER * MROWS);

    __shared__ __align__(16) unsigned short Es[NSTRIP * kD];   // 32KB swizzled [n][k] bf16
    __shared__ __align__(16) float Cs[2][MROWS][CPAD];         // 2 x 16.6KB corner-turn

    // stage E strip, f32 -> bf16, swizzled
    for (int i = tid; i < NSTRIP * 16; i += 512) {
        int r  = i >> 4;
        int c4 = (i & 15) * 4;
        int n  = n0 + r;
        float4 v = (n < kItems) ? *(const float4*)&E[(size_t)n * kD + c4]
                                : make_float4(0.f, 0.f, 0.f, 0.f);
        ushort4 u;
        u.x = f2bf(v.x); u.y = f2bf(v.y); u.z = f2bf(v.z); u.w = f2bf(v.w);
        int byte = (r * 128 + c4 * 2) ^ ((r & 7) << 4);
        *(ushort4*)((char*)Es + byte) = u;
    }
    __syncthreads();

    const int frow = lane & 15;
    const int kq   = lane >> 4;

    // E-fragments: this wave's 32-n group = 2 chunks x 2 k-steps
    bf16x8 efrag[2][2];
#pragma unroll
    for (int nc = 0; nc < 2; ++nc) {
        int brow = wave * 32 + nc * 16 + frow;
        int base = brow * 128 + kq * 16;
        int swz  = (brow & 7) << 4;
        efrag[nc][0] = *(const bf16x8*)((const char*)Es + ((base) ^ swz));
        efrag[nc][1] = *(const bf16x8*)((const char*)Es + ((base + 64) ^ swz));
    }

    // X fragment pointer: m-local row = frow, k = kq*8 (same across waves)
    const unsigned short* xp = Xb + (size_t)(mrow0 + frow) * kD + kq * 8;

    const bool ncol_ok = (n0 + lane * 4 + 3) < kItems;

    // prefetch tile 0
    bf16x8 xc0 = *(const bf16x8*)(xp);
    bf16x8 xc1 = *(const bf16x8*)(xp + 32);

    for (int t = 0; t < NITER; ++t) {
        // prefetch next tile's X fragments (register dbuf)
        bf16x8 xn0, xn1;
        if (t + 1 < NITER) {
            xn0 = *(const bf16x8*)(xp + (size_t)(t + 1) * MROWS * kD);
            xn1 = *(const bf16x8*)(xp + (size_t)(t + 1) * MROWS * kD + 32);
        }

        // issue previous tile's stores first: retire under this iter's compute
        if (t > 0) {
            const int c = (t - 1) & 1;
            const int mbase = mrow0 + (t - 1) * MROWS;
#pragma unroll
            for (int rr = 0; rr < 2; ++rr) {
                int r = wave * 2 + rr;
                f32x4v v = *(const f32x4v*)&Cs[c][r][lane * 4];
                if (ncol_ok)
                    __builtin_nontemporal_store(v,
                        (f32x4v*)(out + (size_t)(mbase + r) * kItems + n0 + lane * 4));
            }
        }

        // MFMA for tile t
        f32x4v acc[2];
#pragma unroll
        for (int nc = 0; nc < 2; ++nc) {
            acc[nc] = (f32x4v){0.f, 0.f, 0.f, 0.f};
            acc[nc] = __builtin_amdgcn_mfma_f32_16x16x32_bf16(efrag[nc][0], xc0, acc[nc], 0, 0, 0);
            acc[nc] = __builtin_amdgcn_mfma_f32_16x16x32_bf16(efrag[nc][1], xc1, acc[nc], 0, 0, 0);
        }

        // corner-turn: D col(lane&15)=m-local, row((lane>>4)*4+reg)=n-local
#pragma unroll
        for (int nc = 0; nc < 2; ++nc)
            *(f32x4v*)&Cs[t & 1][frow][wave * 32 + nc * 16 + kq * 4] = acc[nc];

        __syncthreads();   // Cs[t&1] complete; Cs[(t-1)&1] reads done; stores drained
        xc0 = xn0; xc1 = xn1;
    }

    // epilogue: store last tile
    {
        const int c = (NITER - 1) & 1;
        const int mbase = mrow0 + (NITER - 1) * MROWS;
#pragma unroll
        for (int rr = 0; rr < 2; ++rr) {
            int r = wave * 2 + rr;
            f32x4v v = *(const f32x4v*)&Cs[c][r][lane * 4];
            if (ncol_ok)
                __builtin_nontemporal_store(v,
                    (f32x4v*)(out + (size_t)(mbase + r) * kItems + n0 + lane * 4));
        }
    }
}

extern "C" void kernel_launch(void* const* d_in, const int* in_sizes, int n_in,
                              void* d_out, int out_size, void* d_ws, size_t ws_size,
                              hipStream_t stream) {
    const int*   item_ids = (const int*)d_in[0];
    const float* emb      = (const float*)d_in[1];
    const float* pos_emb  = (const float*)d_in[2];
    const float* Wq       = (const float*)d_in[3];
    const float* Wk       = (const float*)d_in[4];
    const float* Wv       = (const float*)d_in[5];
    const float* W1       = (const float*)d_in[6];
    const float* b1       = (const float*)d_in[7];
    const float* W2       = (const float*)d_in[8];
    const float* b2       = (const float*)d_in[9];
    const float* ln_g     = (const float*)d_in[10];
    const float* ln_b     = (const float*)d_in[11];

    unsigned short* Xb = (unsigned short*)d_ws;   // [B*S, D] bf16, 0.8 MB
    float* out = (float*)d_out;

    transformer_kernel<<<kB, 512, 0, stream>>>(item_ids, emb, pos_emb,
                                               Wq, Wk, Wv, W1, b1, W2, b2,
                                               ln_g, ln_b, Xb);
    dim3 grid((kItems + NSTRIP - 1) / NSTRIP, 2);   // 196 x 2 = 392 blocks
    logits_kernel<<<grid, 512, 0, stream>>>(Xb, emb, out);
}